// Round 4
// baseline (163.192 us; speedup 1.0000x reference)
//
#include <hip/hip_runtime.h>

// Fused deformable-conv net — r15b: identical to r15 (container infra
// failed twice; no counter evidence against the design). Only change:
// pad_kernel is a bounded-grid (2048 blocks) grid-stride loop.
//
// r15 design: global-cell mapping + global gathers from a pre-padded
// workspace tensor (no LDS image at all).
// r14 post-mortem: the p-outer body rewrite doubled VGPR to 128 — the
// r10 k-outer/acc[4][8] body is the only proven 64-VGPR codegen and is
// FROZEN VERBATIM. r15 removes the three structural taxes around it,
// all rooted in the LDS-resident image:
//   - 17% of r10 runtime was SQ_LDS_BANK_CONFLICT on data-dependent
//     bilinear gathers (7.04M cy; odd stride didn't help, r13),
//   - 23.4% of issue was idle lanes (196/256 mapping),
//   - staging 900 LDS words + full-block barrier per block.
// pad_kernel writes zero-padded 30x30 images into d_ws (14.7 MB, fits
// L2/L3); main kernel gathers via wave-uniform base + u32 voffset.
// Weights-only LDS (~1.6 KB). Global-cell grid 3136x256 (exact fit),
// two-temp segmented wave reduce (wave spans <=2 images), memset +
// <=2 atomicAdd per output with single b_fc owner (proven r13).
// Fallback (ws too small): bounds-checked gathers from x directly.

#define NPOS  784
#define NPOOL 1568
#define CELLS 196
#define TPB   256
#define PADW  30
#define PIMG  900

__global__ __launch_bounds__(256) void pad_kernel(
    const float* __restrict__ x, float* __restrict__ xp, int total)
{
    for (int idx = blockIdx.x * TPB + threadIdx.x; idx < total;
         idx += gridDim.x * TPB) {
        int img = idx / PIMG;
        int v   = idx - img * PIMG;
        int r   = v / PADW, c = v - r * PADW;
        float val = 0.f;
        if (r >= 1 && r <= 28 && c >= 1 && c <= 28)
            val = x[(size_t)img * NPOS + (r - 1) * 28 + (c - 1)];
        xp[idx] = val;
    }
}

__device__ __forceinline__ float sample_unpadded(
    const float* __restrict__ xb, int ix, int iy)
{
    unsigned ux = (unsigned)(ix - 1), uy = (unsigned)(iy - 1);
    return (ux <= 27u && uy <= 27u) ? xb[ux * 28u + uy] : 0.f;
}

template<bool PW>
__global__ __launch_bounds__(256) void deform_net_kernel(
    const float* __restrict__ x,       // (B,1,28,28)
    const float* __restrict__ xpad,    // (B,30,30) in ws (PW only)
    const float* __restrict__ w_off,   // (18,1,3,3)
    const float* __restrict__ b_off,   // (18,)
    const float* __restrict__ w_conv,  // (8,1,3,3)
    const float* __restrict__ w_fc,    // (10,1568)
    const float* __restrict__ b_fc,    // (10,)
    float* __restrict__ out,           // (B,10), pre-zeroed
    int Btot)
{
    __shared__ float wo_s[162];
    __shared__ float bo_s[18];
    __shared__ float wc_s[72];
    __shared__ float red[4][3][10];    // [wave][image-slot][channel]

    const int tid   = threadIdx.x;
    const int cell0 = blockIdx.x * TPB;
    const int imgFirst = cell0 / CELLS;
    const int total = Btot * CELLS;

    if (tid < 162) wo_s[tid] = w_off[tid];
    if (tid < 18)  bo_s[tid] = b_off[tid];
    if (tid < 72)  wc_s[tid] = w_conv[tid];
    if (tid < 120) (&red[0][0][0])[tid] = 0.f;
    __syncthreads();                    // weights + red-zero visible

    const int cell = cell0 + tid;
    const int img  = cell / CELLS;      // magic-mul div, once
    const int cim  = cell - img * CELLS;

    float fc[10];
    #pragma unroll
    for (int c = 0; c < 10; c++) fc[c] = 0.f;

    if (cell < total) {
        const int ph = cim / 14, pw = cim - (cim / 14) * 14;
        const int h0 = 2 * ph, w0 = 2 * pw;
        const unsigned base = (unsigned)img * PIMG;   // elem offset in xpad
        const float* __restrict__ xb = x + (size_t)img * NPOS;

        // 4x4 padded-image neighborhood covering all 4 positions' 3x3 taps.
        float nb[16];
        #pragma unroll
        for (int i = 0; i < 4; i++)
            #pragma unroll
            for (int j = 0; j < 4; j++) {
                if constexpr (PW)
                    nb[i * 4 + j] = xpad[base + (unsigned)((h0 + i) * PADW + (w0 + j))];
                else
                    nb[i * 4 + j] = sample_unpadded(xb, h0 + i, w0 + j);
            }

        // ---- r10 champion body, FROZEN (k-outer, acc[4][8]) ----
        float acc[4][8];
        #pragma unroll
        for (int p = 0; p < 4; p++)
            #pragma unroll
            for (int o = 0; o < 8; o++) acc[p][o] = 0.f;

        #pragma unroll
        for (int k = 0; k < 9; k++) {          // deform tap
            const int kx = k / 3, ky = k % 3;
            #pragma unroll
            for (int p = 0; p < 4; p++) {      // position within pool cell
                const int dh = p >> 1, dw = p & 1;

                // offset channels k (x) and k+9 (y): 3x3 conv at (h0+dh, w0+dw)
                float offx = bo_s[k], offy = bo_s[k + 9];
                #pragma unroll
                for (int t = 0; t < 9; t++) {
                    float nv = nb[(dh + t / 3) * 4 + (dw + t % 3)];
                    offx = fmaf(wo_s[k * 9 + t],       nv, offx);
                    offy = fmaf(wo_s[(k + 9) * 9 + t], nv, offy);
                }

                // sample coords in padded frame: p0=(h+1,w+1), pn=(kx-1,ky-1)
                float p_x = (float)(h0 + dh + kx) + offx;
                float p_y = (float)(w0 + dw + ky) + offy;

                float q0x = floorf(p_x), q0y = floorf(p_y);
                float qltx = __builtin_amdgcn_fmed3f(q0x,       0.f, 29.f);
                float qlty = __builtin_amdgcn_fmed3f(q0y,       0.f, 29.f);
                float qrbx = __builtin_amdgcn_fmed3f(q0x + 1.f, 0.f, 29.f);
                float qrby = __builtin_amdgcn_fmed3f(q0y + 1.f, 0.f, 29.f);
                float px   = __builtin_amdgcn_fmed3f(p_x,       0.f, 29.f);
                float py   = __builtin_amdgcn_fmed3f(p_y,       0.f, 29.f);

                float gltx = 1.f + (qltx - px);
                float glty = 1.f + (qlty - py);
                float grbx = 1.f - (qrbx - px);
                float grby = 1.f - (qrby - py);

                int ilx = (int)qltx, ily = (int)qlty;
                int irx = (int)qrbx, iry = (int)qrby;

                float xlt, xrb, xlb, xrt;
                if constexpr (PW) {
                    unsigned rL = base + (unsigned)(ilx * PADW);
                    unsigned rR = base + (unsigned)(irx * PADW);
                    xlt = xpad[rL + (unsigned)ily];
                    xrb = xpad[rR + (unsigned)iry];
                    xlb = xpad[rL + (unsigned)iry];
                    xrt = xpad[rR + (unsigned)ily];
                } else {
                    xlt = sample_unpadded(xb, ilx, ily);
                    xrb = sample_unpadded(xb, irx, iry);
                    xlb = sample_unpadded(xb, ilx, iry);
                    xrt = sample_unpadded(xb, irx, ily);
                }

                // factored bilinear combine (same clip semantics)
                float s = gltx * (glty * xlt + grby * xlb)
                        + grbx * (glty * xrt + grby * xrb);

                #pragma unroll
                for (int o = 0; o < 8; o++)
                    acc[p][o] = fmaf(wc_s[o * 9 + k], s, acc[p][o]);
            }
        }

        // relu + 2x2 maxpool in registers, then FC partial sums (o-outer).
        #pragma unroll
        for (int o = 0; o < 8; o++) {
            float m = fmaxf(fmaxf(acc[0][o], acc[1][o]),
                            fmaxf(acc[2][o], acc[3][o]));
            m = fmaxf(m, 0.f);
            const float* wrow = w_fc + o * CELLS + cim;  // flat idx o*196+cell
            #pragma unroll
            for (int c = 0; c < 10; c++)
                fc[c] = fmaf(m, wrow[c * NPOOL], fc[c]);
        }
        // ---- end frozen body ----
    }

    // Image-segmented wave reduction. A wave's 64 consecutive cells span
    // at most 2 images. sLo/sHi are wave-uniform scalars.
    const int wave = tid >> 6, lane = tid & 63;
    const int wc0 = cell0 + (wave << 6);
    const int sLo = wc0 / CELLS - imgFirst;
    const int sHi = (wc0 + 63) / CELLS - imgFirst;
    const int slot = img - imgFirst;

    if (sLo == sHi) {
        #pragma unroll
        for (int c = 0; c < 10; c++) {
            float a = fc[c];
            #pragma unroll
            for (int sh = 32; sh > 0; sh >>= 1)
                a += __shfl_down(a, sh, 64);
            if (lane == 0) red[wave][sLo][c] = a;
        }
    } else {
        const bool lo = (slot == sLo);
        #pragma unroll
        for (int c = 0; c < 10; c++) {
            float a = lo ? fc[c] : 0.f;
            float b = lo ? 0.f : fc[c];
            #pragma unroll
            for (int sh = 32; sh > 0; sh >>= 1) {
                a += __shfl_down(a, sh, 64);
                b += __shfl_down(b, sh, 64);
            }
            if (lane == 0) {
                red[wave][sLo][c] = a;
                red[wave][sHi][c] = b;
            }
        }
    }
    __syncthreads();

    // Cross-wave sum per (image-slot, channel); owner block folds b_fc.
    if (tid < 30) {
        const int s = tid / 10, c = tid - (tid / 10) * 10;
        const int oimg = imgFirst + s;
        if (oimg < Btot) {
            float v = red[0][s][c] + red[1][s][c]
                    + red[2][s][c] + red[3][s][c];
            const int c0im = oimg * CELLS - cell0;
            if (c0im >= 0 && c0im < TPB) v += b_fc[c];   // exactly one owner
            if (v != 0.f) atomicAdd(out + oimg * 10 + c, v);
        }
    }
}

extern "C" void kernel_launch(void* const* d_in, const int* in_sizes, int n_in,
                              void* d_out, int out_size, void* d_ws, size_t ws_size,
                              hipStream_t stream) {
    const float* x      = (const float*)d_in[0];
    const float* w_off  = (const float*)d_in[1];
    const float* b_off  = (const float*)d_in[2];
    const float* w_conv = (const float*)d_in[3];
    const float* w_fc   = (const float*)d_in[4];
    const float* b_fc   = (const float*)d_in[5];
    float* out = (float*)d_out;

    const int B = in_sizes[0] / NPOS;
    const int nblk = (B * CELLS + TPB - 1) / TPB;   // 3136 for B=4096
    const size_t padBytes = (size_t)B * PIMG * sizeof(float);

    hipMemsetAsync(d_out, 0, (size_t)B * 10 * sizeof(float), stream);

    if (d_ws != nullptr && ws_size >= padBytes) {
        float* xp = (float*)d_ws;
        const int ptotal = B * PIMG;
        int pblk = (ptotal + TPB - 1) / TPB;
        if (pblk > 2048) pblk = 2048;
        pad_kernel<<<pblk, TPB, 0, stream>>>(x, xp, ptotal);
        deform_net_kernel<true><<<nblk, TPB, 0, stream>>>(
            x, xp, w_off, b_off, w_conv, w_fc, b_fc, out, B);
    } else {
        deform_net_kernel<false><<<nblk, TPB, 0, stream>>>(
            x, nullptr, w_off, b_off, w_conv, w_fc, b_fc, out, B);
    }
}